// Round 1
// baseline (523.923 us; speedup 1.0000x reference)
//
#include <hip/hip_runtime.h>

typedef unsigned long long u64;
typedef unsigned int u32;

#define N0 147456   // 384*384
#define N1 36864    // 192*192
#define NTOT 184320
#define KKP 512
#define KM 128
#define CAP_CAND 16384
#define NBINS 16384
#define CAP_COL 2048

struct InPtrs {
  const float* rep[2][2];   // [img][level]
  const float* rel[2][2];
  const float* desc[2][2];
};

// ---------------- candidate generation ----------------
// slot = img*2 + b. Key = (score_bits<<32) | ~pixel_index  ->  descending sort
// == descending score, ties broken by LOWER index (matches lax.top_k).
__global__ void cand_kernel(InPtrs P, u64* __restrict__ cand, int* __restrict__ cnt) {
  int slot = blockIdx.y;
  int img = slot >> 1, b = slot & 1;
  int p = blockIdx.x * blockDim.x + threadIdx.x;
  if (p >= NTOT) return;
  int level, W, q, Npix;
  if (p < N0) { level = 0; W = 384; q = p; Npix = N0; }
  else        { level = 1; W = 192; q = p - N0; Npix = N1; }
  const float* rp = P.rep[img][level] + (size_t)b * Npix;
  const float* rl = P.rel[img][level] + (size_t)b * Npix;
  float v = rp[q];
  float m = sqrtf(v * rl[q]);
  if (!(m >= 0.7f)) return;
  int y = q / W, x = q - y * W;
  // 3x3 local max with -inf SAME padding: center >= all in-bounds neighbors
  int y0 = (y > 0) ? y - 1 : y, y1 = (y < W - 1) ? y + 1 : y;
  int x0 = (x > 0) ? x - 1 : x, x1 = (x < W - 1) ? x + 1 : x;
  for (int yy = y0; yy <= y1; ++yy)
    for (int xx = x0; xx <= x1; ++xx)
      if (rp[yy * W + xx] > v) return;
  u32 sb = __float_as_uint(m);
  u64 key = ((u64)sb << 32) | (u32)(~(u32)p);
  int pos = atomicAdd(&cnt[slot], 1);
  if (pos < CAP_CAND) cand[(size_t)slot * CAP_CAND + pos] = key;
}

// ---------------- bitonic sort of 2048 u64 keys in LDS, descending ----------------
__device__ inline void bitonic2048(u64* k, int t) {
  for (int size = 2; size <= 2048; size <<= 1) {
    for (int j = size >> 1; j > 0; j >>= 1) {
      __syncthreads();
      for (int i = t; i < 2048; i += 1024) {
        int ixj = i ^ j;
        if (ixj > i) {
          u64 a = k[i], b = k[ixj];
          bool desc = ((i & size) == 0);
          if (desc ? (a < b) : (a > b)) { k[i] = b; k[ixj] = a; }
        }
      }
    }
  }
  __syncthreads();
}

// ---------------- generic single-block top-K select+sort ----------------
// histogram radix-select on bin = (key >> (32+shift)) & (NBINS-1) (must be
// monotone over the key range), then exact bitonic sort of the <=2048 survivors.
__global__ __launch_bounds__(1024) void select_topk(const u64* __restrict__ keys_all,
                                                    const int* __restrict__ cnt,
                                                    int cap, int K, int shift,
                                                    u64* __restrict__ out) {
  __shared__ int hist[NBINS];
  __shared__ u64 kbuf[CAP_COL];
  __shared__ int part[1024];
  __shared__ int Bbin, colcnt;
  int slot = blockIdx.x;
  int t = threadIdx.x;
  const u64* keys = keys_all + (size_t)slot * cap;
  int n = cnt[slot]; if (n > cap) n = cap;
  for (int i = t; i < NBINS; i += 1024) hist[i] = 0;
  if (t == 0) { Bbin = 0; colcnt = 0; }
  __syncthreads();
  for (int i = t; i < n; i += 1024) {
    u32 bin = (u32)((keys[i] >> (32 + shift)) & (NBINS - 1));
    atomicAdd(&hist[bin], 1);
  }
  __syncthreads();
  const int BPT = NBINS / 1024;
  int base = t * BPT;
  int lsum = 0;
  for (int j = 0; j < BPT; ++j) lsum += hist[base + j];
  part[t] = lsum;
  __syncthreads();
  for (int off = 1; off < 1024; off <<= 1) {   // suffix scan (Hillis-Steele)
    int v = (t + off < 1024) ? part[t + off] : 0;
    __syncthreads();
    part[t] += v;
    __syncthreads();
  }
  int Sab = part[t] - lsum;   // count strictly above my bin range
  if (Sab < K && Sab + lsum >= K) {
    int c = Sab;
    for (int j = BPT - 1; j >= 0; --j) {
      c += hist[base + j];
      if (c >= K) { Bbin = base + j; break; }
    }
  }
  __syncthreads();
  int Bb = Bbin;
  for (int i = t; i < n; i += 1024) {
    u64 kk = keys[i];
    if ((int)((kk >> (32 + shift)) & (NBINS - 1)) >= Bb) {
      int pos = atomicAdd(&colcnt, 1);
      if (pos < CAP_COL) kbuf[pos] = kk;
    }
  }
  __syncthreads();
  int nc = colcnt; if (nc > CAP_COL) nc = CAP_COL;
  for (int i = t; i < CAP_COL; i += 1024) if (i >= nc) kbuf[i] = 0;
  __syncthreads();
  bitonic2048(kbuf, t);
  for (int i = t; i < K; i += 1024) out[(size_t)slot * K + i] = kbuf[i];
}

// ---------------- decode keypoint keys ----------------
__global__ void kp_decode(const u64* __restrict__ kp_keys,
                          float* __restrict__ kp_loc, int* __restrict__ kp_level,
                          int* __restrict__ kp_p, float* __restrict__ kp_score) {
  int slot = blockIdx.x;
  int k = threadIdx.x;      // 512
  u64 key = kp_keys[slot * KKP + k];
  float s = __uint_as_float((u32)(key >> 32));
  u32 idx = ~(u32)key;
  int level, p, W, scale;
  if (idx < N0) { level = 0; p = (int)idx; W = 384; scale = 1; }
  else          { level = 1; p = (int)(idx - N0); W = 192; scale = 2; }
  if (p < 0 || p >= (level ? N1 : N0)) { p = 0; s = 0.f; }  // pad guard
  int y = p / W, x = p - y * W;
  kp_loc[(slot * 2 + 0) * KKP + k] = (float)(y * scale);
  kp_loc[(slot * 2 + 1) * KKP + k] = (float)(x * scale);
  kp_level[slot * KKP + k] = level;
  kp_p[slot * KKP + k] = p;
  kp_score[slot * KKP + k] = s;
}

// ---------------- gather descriptors * score ----------------
__global__ void gather_kernel(InPtrs P, const int* __restrict__ kp_level,
                              const int* __restrict__ kp_p, const float* __restrict__ kp_score,
                              float* __restrict__ dA) {
  int slot = blockIdx.y;
  int k = blockIdx.x;
  int c = threadIdx.x;      // 128
  int img = slot >> 1, b = slot & 1;
  int level = kp_level[slot * KKP + k];
  int p = kp_p[slot * KKP + k];
  float s = kp_score[slot * KKP + k];
  const float* dptr = P.desc[img][level];
  size_t HW = level ? N1 : N0;
  float v = dptr[((size_t)b * 128 + c) * HW + p];
  dA[((size_t)slot * KKP + k) * 128 + c] = v * s;
}

// ---------------- small fp32 GEMM: S[b][k][l] = dot(A_k, B_l) over C=128 ----------------
__global__ void gemm_kernel(const float* __restrict__ dA, float* __restrict__ S) {
  __shared__ float tA[16][132], tB[16][132];   // +4 pad: 2-way LDS aliasing (free)
  int b = blockIdx.z;
  const float* A  = dA + (size_t)b * KKP * 128;        // slot img0 = b
  const float* Bm = dA + (size_t)(2 + b) * KKP * 128;  // slot img1 = 2+b
  int row0 = blockIdx.y * 16, col0 = blockIdx.x * 16;
  int t = threadIdx.y * 16 + threadIdx.x;
  for (int i = t; i < 2048; i += 256) {
    int r = i >> 7, c = i & 127;
    tA[r][c] = A[(row0 + r) * 128 + c];
    tB[r][c] = Bm[(col0 + r) * 128 + c];
  }
  __syncthreads();
  float acc = 0.f;
  const float* ar = tA[threadIdx.y];
  const float* br = tB[threadIdx.x];
  for (int c = 0; c < 128; ++c) acc += ar[c] * br[c];
  S[(size_t)b * KKP * KKP + (size_t)(row0 + threadIdx.y) * KKP + (col0 + threadIdx.x)] = acc;
}

// ---------------- match histogram (order-preserving float->u32, bin = key>>18) ----------------
__device__ inline u32 fkey32(float v) {
  u32 bits = __float_as_uint(v);
  return (bits & 0x80000000u) ? ~bits : (bits | 0x80000000u);
}

__global__ __launch_bounds__(1024) void mhist_kernel(const float* __restrict__ S, int* __restrict__ hist) {
  __shared__ int lh[NBINS];
  int t = threadIdx.x;
  for (int i = t; i < NBINS; i += 1024) lh[i] = 0;
  __syncthreads();
  int b = blockIdx.y;
  const float* Sb = S + (size_t)b * KKP * KKP;
  int base = blockIdx.x * 16384;
  for (int i = 0; i < 16; ++i) {
    u32 key = fkey32(Sb[base + i * 1024 + t]);
    atomicAdd(&lh[key >> 18], 1);
  }
  __syncthreads();
  for (int i = t; i < NBINS; i += 1024) {
    int v = lh[i];
    if (v) atomicAdd(&hist[b * NBINS + i], v);
  }
}

__global__ __launch_bounds__(1024) void mscan_kernel(const int* __restrict__ hist, int* __restrict__ thrB) {
  __shared__ int part[1024];
  __shared__ int Bbin;
  int b = blockIdx.x;
  int t = threadIdx.x;
  const int* h = hist + b * NBINS;
  if (t == 0) Bbin = 0;
  const int BPT = NBINS / 1024;
  int base = t * BPT;
  int lsum = 0;
  for (int j = 0; j < BPT; ++j) lsum += h[base + j];
  part[t] = lsum;
  __syncthreads();
  for (int off = 1; off < 1024; off <<= 1) {
    int v = (t + off < 1024) ? part[t + off] : 0;
    __syncthreads();
    part[t] += v;
    __syncthreads();
  }
  int Sab = part[t] - lsum;
  if (Sab < KM && Sab + lsum >= KM) {
    int c = Sab;
    for (int j = BPT - 1; j >= 0; --j) {
      c += h[base + j];
      if (c >= KM) { Bbin = base + j; break; }
    }
  }
  __syncthreads();
  if (t == 0) thrB[b] = Bbin;
}

__global__ void mcollect_kernel(const float* __restrict__ S, const int* __restrict__ thrB,
                                u64* __restrict__ mcol, int* __restrict__ cnt) {
  int b = blockIdx.y;
  int flat = blockIdx.x * blockDim.x + threadIdx.x;   // < 262144
  u32 key32 = fkey32(S[(size_t)b * KKP * KKP + flat]);
  if ((int)(key32 >> 18) >= thrB[b]) {
    int pos = atomicAdd(&cnt[b], 1);
    if (pos < CAP_COL) mcol[(size_t)b * CAP_COL + pos] = ((u64)key32 << 32) | (u32)(~(u32)flat);
  }
}

__global__ __launch_bounds__(1024) void msort_out(const u64* __restrict__ mcol, const int* __restrict__ cnt,
                                                  const float* __restrict__ kp_loc, float* __restrict__ out) {
  __shared__ u64 kbuf[CAP_COL];
  int b = blockIdx.x;
  int t = threadIdx.x;
  int n = cnt[b]; if (n > CAP_COL) n = CAP_COL;
  for (int i = t; i < CAP_COL; i += 1024) kbuf[i] = (i < n) ? mcol[(size_t)b * CAP_COL + i] : 0ULL;
  __syncthreads();
  bitonic2048(kbuf, t);
  if (t < KM) {
    u64 key = kbuf[t];
    u32 flat = ~(u32)key;
    int i1 = (int)(flat >> 9), i2 = (int)(flat & 511);
    if (i1 >= KKP) { i1 = 0; i2 = 0; }  // pad guard (never hit: 262144 finite scores)
    int slot1 = b, slot2 = 2 + b;
    out[(b * 4 + 0) * KM + t] = kp_loc[(slot1 * 2 + 0) * KKP + i1];
    out[(b * 4 + 1) * KM + t] = kp_loc[(slot1 * 2 + 1) * KKP + i1];
    out[(b * 4 + 2) * KM + t] = kp_loc[(slot2 * 2 + 0) * KKP + i2];
    out[(b * 4 + 3) * KM + t] = kp_loc[(slot2 * 2 + 1) * KKP + i2];
  }
}

extern "C" void kernel_launch(void* const* d_in, const int* in_sizes, int n_in,
                              void* d_out, int out_size, void* d_ws, size_t ws_size,
                              hipStream_t stream) {
  (void)in_sizes; (void)n_in; (void)out_size; (void)ws_size;
  InPtrs P;
  P.rep[0][0] = (const float*)d_in[0];  P.rel[0][0] = (const float*)d_in[1];  P.desc[0][0] = (const float*)d_in[2];
  P.rep[0][1] = (const float*)d_in[3];  P.rel[0][1] = (const float*)d_in[4];  P.desc[0][1] = (const float*)d_in[5];
  P.rep[1][0] = (const float*)d_in[6];  P.rel[1][0] = (const float*)d_in[7];  P.desc[1][0] = (const float*)d_in[8];
  P.rep[1][1] = (const float*)d_in[9];  P.rel[1][1] = (const float*)d_in[10]; P.desc[1][1] = (const float*)d_in[11];

  char* ws = (char*)d_ws;
  int*   cnt_cand  = (int*)(ws + 0);    // 4
  int*   cnt_match = (int*)(ws + 16);   // 2
  int*   thrB      = (int*)(ws + 24);   // 2
  int*   mhist     = (int*)(ws + 32);   // 2*16384
  size_t off = 32 + (size_t)2 * NBINS * 4;                 // 131104, zeroed region end
  u64*   cand    = (u64*)(ws + off);  off += 4ULL * CAP_CAND * 8;
  u64*   kp_keys = (u64*)(ws + off);  off += 4ULL * KKP * 8;
  float* kp_loc  = (float*)(ws + off); off += 4ULL * 2 * KKP * 4;
  int*   kp_level= (int*)(ws + off);  off += 4ULL * KKP * 4;
  int*   kp_p    = (int*)(ws + off);  off += 4ULL * KKP * 4;
  float* kp_score= (float*)(ws + off); off += 4ULL * KKP * 4;
  float* dA      = (float*)(ws + off); off += 4ULL * KKP * 128 * 4;
  float* S       = (float*)(ws + off); off += 2ULL * KKP * KKP * 4;
  u64*   mcol    = (u64*)(ws + off);  off += 2ULL * CAP_COL * 8;   // ~3.9 MB total

  // zero counters + match histogram (ws is re-poisoned 0xAA before every call)
  hipMemsetAsync(d_ws, 0, 32 + (size_t)2 * NBINS * 4, stream);

  cand_kernel<<<dim3((NTOT + 255) / 256, 4), 256, 0, stream>>>(P, cand, cnt_cand);
  // keypoint keys all have exponent 126 (score in [0.7,1)) -> shift=9 is monotone, no wrap
  select_topk<<<4, 1024, 0, stream>>>(cand, cnt_cand, CAP_CAND, KKP, 9, kp_keys);
  kp_decode<<<4, KKP, 0, stream>>>(kp_keys, kp_loc, kp_level, kp_p, kp_score);
  gather_kernel<<<dim3(KKP, 4), 128, 0, stream>>>(P, kp_level, kp_p, kp_score, dA);
  gemm_kernel<<<dim3(32, 32, 2), dim3(16, 16), 0, stream>>>(dA, S);
  mhist_kernel<<<dim3(16, 2), 1024, 0, stream>>>(S, mhist);
  mscan_kernel<<<2, 1024, 0, stream>>>(mhist, thrB);
  mcollect_kernel<<<dim3(1024, 2), 256, 0, stream>>>(S, thrB, mcol, cnt_match);
  msort_out<<<2, 1024, 0, stream>>>(mcol, cnt_match, kp_loc, (float*)d_out);
}

// Round 2
// 412.169 us; speedup vs baseline: 1.2711x; 1.2711x over previous
//
#include <hip/hip_runtime.h>

typedef unsigned long long u64;
typedef unsigned int u32;

#define N0 147456   // 384*384
#define N1 36864    // 192*192
#define NTOT 184320 // = 720 * 256 exactly
#define KKP 512
#define KM 128
#define CAP_CAND 16384
#define NBINS 16384
#define CAP_COL 2048

struct InPtrs {
  const float* rep[2][2];   // [img][level]
  const float* rel[2][2];
  const float* desc[2][2];
};

// ---------------- candidate generation ----------------
// slot = img*2 + b. Key = (score_bits<<32) | ~pixel_index  ->  descending sort
// == descending score, ties broken by LOWER index (matches lax.top_k).
// Block-aggregated append: LDS atomics + ONE global atomic per block
// (R1 post-mortem: ~37K per-lane atomics on one cacheline = ~133 us serial).
__global__ __launch_bounds__(256) void cand_kernel(InPtrs P, u64* __restrict__ cand,
                                                   int* __restrict__ cnt) {
  __shared__ u64 buf[256];
  __shared__ int lcnt, gbase;
  int slot = blockIdx.y;
  int img = slot >> 1, b = slot & 1;
  int p = blockIdx.x * 256 + threadIdx.x;   // NTOT == 720*256, no tail
  if (threadIdx.x == 0) lcnt = 0;
  __syncthreads();
  int level, W, q, Npix;
  if (p < N0) { level = 0; W = 384; q = p; Npix = N0; }
  else        { level = 1; W = 192; q = p - N0; Npix = N1; }
  const float* rp = P.rep[img][level] + (size_t)b * Npix;
  const float* rl = P.rel[img][level] + (size_t)b * Npix;
  float v = rp[q];
  float m = sqrtf(v * rl[q]);
  bool ok = (m >= 0.7f);
  if (ok) {
    int y = q / W, x = q - y * W;   // square levels: H == W
    int y0 = (y > 0) ? y - 1 : y, y1 = (y < W - 1) ? y + 1 : y;
    int x0 = (x > 0) ? x - 1 : x, x1 = (x < W - 1) ? x + 1 : x;
    for (int yy = y0; yy <= y1 && ok; ++yy)
      for (int xx = x0; xx <= x1; ++xx)
        if (rp[yy * W + xx] > v) { ok = false; break; }
  }
  if (ok) {
    u32 sb = __float_as_uint(m);
    int pos = atomicAdd(&lcnt, 1);          // LDS atomic: cheap, per-CU
    buf[pos] = ((u64)sb << 32) | (u32)(~(u32)p);
  }
  __syncthreads();
  if (threadIdx.x == 0) gbase = lcnt ? atomicAdd(&cnt[slot * 16], lcnt) : 0;
  __syncthreads();
  int n = lcnt;
  if ((int)threadIdx.x < n) {
    int pos = gbase + (int)threadIdx.x;
    if (pos < CAP_CAND) cand[(size_t)slot * CAP_CAND + pos] = buf[threadIdx.x];
  }
}

// ---------------- bitonic sort of 2048 u64 keys in LDS, descending ----------------
__device__ inline void bitonic2048(u64* k, int t) {
  for (int size = 2; size <= 2048; size <<= 1) {
    for (int j = size >> 1; j > 0; j >>= 1) {
      __syncthreads();
      for (int i = t; i < 2048; i += 1024) {
        int ixj = i ^ j;
        if (ixj > i) {
          u64 a = k[i], b = k[ixj];
          bool desc = ((i & size) == 0);
          if (desc ? (a < b) : (a > b)) { k[i] = b; k[ixj] = a; }
        }
      }
    }
  }
  __syncthreads();
}

// ---------------- keypoint top-512: radix-select + exact sort + decode ----------------
// histogram bin = (key >> 41) & 16383 = top-14 mantissa bits; all scores are in
// [0.7,1) (exponent 126) so this is monotone. Fused decode epilogue (was kp_decode).
__global__ __launch_bounds__(1024) void kp_select(const u64* __restrict__ keys_all,
                                                  const int* __restrict__ cnt,
                                                  float* __restrict__ kp_loc,
                                                  int* __restrict__ kp_level,
                                                  int* __restrict__ kp_p,
                                                  float* __restrict__ kp_score) {
  __shared__ int hist[NBINS];
  __shared__ u64 kbuf[CAP_COL];
  __shared__ int part[1024];
  __shared__ int Bbin, colcnt;
  int slot = blockIdx.x;
  int t = threadIdx.x;
  const u64* keys = keys_all + (size_t)slot * CAP_CAND;
  int n = cnt[slot * 16]; if (n > CAP_CAND) n = CAP_CAND;
  for (int i = t; i < NBINS; i += 1024) hist[i] = 0;
  if (t == 0) { Bbin = 0; colcnt = 0; }
  __syncthreads();
  for (int i = t; i < n; i += 1024) {
    u32 bin = (u32)((keys[i] >> 41) & (NBINS - 1));
    atomicAdd(&hist[bin], 1);
  }
  __syncthreads();
  const int BPT = NBINS / 1024;
  int base = t * BPT;
  int lsum = 0;
  for (int j = 0; j < BPT; ++j) lsum += hist[base + j];
  part[t] = lsum;
  __syncthreads();
  for (int off = 1; off < 1024; off <<= 1) {   // suffix scan
    int v = (t + off < 1024) ? part[t + off] : 0;
    __syncthreads();
    part[t] += v;
    __syncthreads();
  }
  int Sab = part[t] - lsum;   // count strictly above my bin range
  if (Sab < KKP && Sab + lsum >= KKP) {
    int c = Sab;
    for (int j = BPT - 1; j >= 0; --j) {
      c += hist[base + j];
      if (c >= KKP) { Bbin = base + j; break; }
    }
  }
  __syncthreads();
  int Bb = Bbin;
  for (int i = t; i < n; i += 1024) {
    u64 kk = keys[i];
    if ((int)((kk >> 41) & (NBINS - 1)) >= Bb) {
      int pos = atomicAdd(&colcnt, 1);
      if (pos < CAP_COL) kbuf[pos] = kk;
    }
  }
  __syncthreads();
  int nc = colcnt; if (nc > CAP_COL) nc = CAP_COL;
  for (int i = t; i < CAP_COL; i += 1024) if (i >= nc) kbuf[i] = 0;
  __syncthreads();
  bitonic2048(kbuf, t);
  // fused decode (t < 512)
  if (t < KKP) {
    u64 key = kbuf[t];
    float s = __uint_as_float((u32)(key >> 32));
    u32 idx = ~(u32)key;
    int level, p, W, scale;
    if (idx < N0) { level = 0; p = (int)idx; W = 384; scale = 1; }
    else          { level = 1; p = (int)(idx - N0); W = 192; scale = 2; }
    if (p < 0 || p >= (level ? N1 : N0)) { p = 0; s = 0.f; }  // pad guard
    int y = p / W, x = p - y * W;
    kp_loc[(slot * 2 + 0) * KKP + t] = (float)(y * scale);
    kp_loc[(slot * 2 + 1) * KKP + t] = (float)(x * scale);
    kp_level[slot * KKP + t] = level;
    kp_p[slot * KKP + t] = p;
    kp_score[slot * KKP + t] = s;
  }
}

// ---------------- gather descriptors * score ----------------
__global__ void gather_kernel(InPtrs P, const int* __restrict__ kp_level,
                              const int* __restrict__ kp_p, const float* __restrict__ kp_score,
                              float* __restrict__ dA) {
  int slot = blockIdx.y;
  int k = blockIdx.x;
  int c = threadIdx.x;      // 128
  int img = slot >> 1, b = slot & 1;
  int level = kp_level[slot * KKP + k];
  int p = kp_p[slot * KKP + k];
  float s = kp_score[slot * KKP + k];
  const float* dptr = P.desc[img][level];
  size_t HW = level ? N1 : N0;
  float v = dptr[((size_t)b * 128 + c) * HW + p];
  dA[((size_t)slot * KKP + k) * 128 + c] = v * s;
}

// ---------------- small fp32 GEMM: S[b][k][l] = dot(A_k, B_l) over C=128 ----------------
__global__ void gemm_kernel(const float* __restrict__ dA, float* __restrict__ S) {
  __shared__ float tA[16][132], tB[16][132];   // +4 pad: 2-way LDS aliasing (free)
  int b = blockIdx.z;
  const float* A  = dA + (size_t)b * KKP * 128;        // slot img0 = b
  const float* Bm = dA + (size_t)(2 + b) * KKP * 128;  // slot img1 = 2+b
  int row0 = blockIdx.y * 16, col0 = blockIdx.x * 16;
  int t = threadIdx.y * 16 + threadIdx.x;
  for (int i = t; i < 2048; i += 256) {
    int r = i >> 7, c = i & 127;
    tA[r][c] = A[(row0 + r) * 128 + c];
    tB[r][c] = Bm[(col0 + r) * 128 + c];
  }
  __syncthreads();
  float acc = 0.f;
  const float* ar = tA[threadIdx.y];
  const float* br = tB[threadIdx.x];
  for (int c = 0; c < 128; ++c) acc += ar[c] * br[c];
  S[(size_t)b * KKP * KKP + (size_t)(row0 + threadIdx.y) * KKP + (col0 + threadIdx.x)] = acc;
}

// ---------------- match histogram (order-preserving float->u32, bin = key>>18) ----------------
__device__ inline u32 fkey32(float v) {
  u32 bits = __float_as_uint(v);
  return (bits & 0x80000000u) ? ~bits : (bits | 0x80000000u);
}

__global__ __launch_bounds__(1024) void mhist_kernel(const float* __restrict__ S, int* __restrict__ hist) {
  __shared__ int lh[NBINS];
  int t = threadIdx.x;
  for (int i = t; i < NBINS; i += 1024) lh[i] = 0;
  __syncthreads();
  int b = blockIdx.y;
  const float* Sb = S + (size_t)b * KKP * KKP;
  int base = blockIdx.x * 16384;
  for (int i = 0; i < 16; ++i) {
    u32 key = fkey32(Sb[base + i * 1024 + t]);
    atomicAdd(&lh[key >> 18], 1);
  }
  __syncthreads();
  for (int i = t; i < NBINS; i += 1024) {
    int v = lh[i];
    if (v) atomicAdd(&hist[b * NBINS + i], v);
  }
}

__global__ __launch_bounds__(1024) void mscan_kernel(const int* __restrict__ hist, int* __restrict__ thrB) {
  __shared__ int part[1024];
  __shared__ int Bbin;
  int b = blockIdx.x;
  int t = threadIdx.x;
  const int* h = hist + b * NBINS;
  if (t == 0) Bbin = 0;
  const int BPT = NBINS / 1024;
  int base = t * BPT;
  int lsum = 0;
  for (int j = 0; j < BPT; ++j) lsum += h[base + j];
  part[t] = lsum;
  __syncthreads();
  for (int off = 1; off < 1024; off <<= 1) {
    int v = (t + off < 1024) ? part[t + off] : 0;
    __syncthreads();
    part[t] += v;
    __syncthreads();
  }
  int Sab = part[t] - lsum;
  if (Sab < KM && Sab + lsum >= KM) {
    int c = Sab;
    for (int j = BPT - 1; j >= 0; --j) {
      c += h[base + j];
      if (c >= KM) { Bbin = base + j; break; }
    }
  }
  __syncthreads();
  if (t == 0) thrB[b] = Bbin;
}

// block-aggregated collect (same LDS-append pattern as cand_kernel)
__global__ __launch_bounds__(256) void mcollect_kernel(const float* __restrict__ S,
                                                       const int* __restrict__ thrB,
                                                       u64* __restrict__ mcol,
                                                       int* __restrict__ cnt) {
  __shared__ u64 buf[256];
  __shared__ int lcnt, gbase;
  int b = blockIdx.y;
  int flat = blockIdx.x * 256 + threadIdx.x;   // < 262144
  if (threadIdx.x == 0) lcnt = 0;
  __syncthreads();
  u32 key32 = fkey32(S[(size_t)b * KKP * KKP + flat]);
  if ((int)(key32 >> 18) >= thrB[b]) {
    int pos = atomicAdd(&lcnt, 1);
    buf[pos] = ((u64)key32 << 32) | (u32)(~(u32)flat);
  }
  __syncthreads();
  if (threadIdx.x == 0) gbase = lcnt ? atomicAdd(&cnt[b * 16], lcnt) : 0;
  __syncthreads();
  int n = lcnt;
  if ((int)threadIdx.x < n) {
    int pos = gbase + (int)threadIdx.x;
    if (pos < CAP_COL) mcol[(size_t)b * CAP_COL + pos] = buf[threadIdx.x];
  }
}

__global__ __launch_bounds__(1024) void msort_out(const u64* __restrict__ mcol, const int* __restrict__ cnt,
                                                  const float* __restrict__ kp_loc, float* __restrict__ out) {
  __shared__ u64 kbuf[CAP_COL];
  int b = blockIdx.x;
  int t = threadIdx.x;
  int n = cnt[b * 16]; if (n > CAP_COL) n = CAP_COL;
  for (int i = t; i < CAP_COL; i += 1024) kbuf[i] = (i < n) ? mcol[(size_t)b * CAP_COL + i] : 0ULL;
  __syncthreads();
  bitonic2048(kbuf, t);
  if (t < KM) {
    u64 key = kbuf[t];
    u32 flat = ~(u32)key;
    int i1 = (int)(flat >> 9), i2 = (int)(flat & 511);
    if (i1 >= KKP) { i1 = 0; i2 = 0; }  // pad guard (never hit: 262144 finite scores)
    int slot1 = b, slot2 = 2 + b;
    out[(b * 4 + 0) * KM + t] = kp_loc[(slot1 * 2 + 0) * KKP + i1];
    out[(b * 4 + 1) * KM + t] = kp_loc[(slot1 * 2 + 1) * KKP + i1];
    out[(b * 4 + 2) * KM + t] = kp_loc[(slot2 * 2 + 0) * KKP + i2];
    out[(b * 4 + 3) * KM + t] = kp_loc[(slot2 * 2 + 1) * KKP + i2];
  }
}

extern "C" void kernel_launch(void* const* d_in, const int* in_sizes, int n_in,
                              void* d_out, int out_size, void* d_ws, size_t ws_size,
                              hipStream_t stream) {
  (void)in_sizes; (void)n_in; (void)out_size; (void)ws_size;
  InPtrs P;
  P.rep[0][0] = (const float*)d_in[0];  P.rel[0][0] = (const float*)d_in[1];  P.desc[0][0] = (const float*)d_in[2];
  P.rep[0][1] = (const float*)d_in[3];  P.rel[0][1] = (const float*)d_in[4];  P.desc[0][1] = (const float*)d_in[5];
  P.rep[1][0] = (const float*)d_in[6];  P.rel[1][0] = (const float*)d_in[7];  P.desc[1][0] = (const float*)d_in[8];
  P.rep[1][1] = (const float*)d_in[9];  P.rel[1][1] = (const float*)d_in[10]; P.desc[1][1] = (const float*)d_in[11];

  char* ws = (char*)d_ws;
  // counters: each slot's counter on its own 64B cacheline (stride-16 ints)
  int*   cnt_cand  = (int*)(ws + 0);      // cnt_cand[slot*16], 4 slots -> 256B
  int*   cnt_match = (int*)(ws + 256);    // cnt_match[b*16], 2 -> 128B
  int*   thrB      = (int*)(ws + 512);    // 2 ints
  int*   mhist     = (int*)(ws + 1024);   // 2*16384*4 = 131072
  size_t off = 1024 + (size_t)2 * NBINS * 4;               // zeroed region end
  u64*   cand    = (u64*)(ws + off);  off += 4ULL * CAP_CAND * 8;
  float* kp_loc  = (float*)(ws + off); off += 4ULL * 2 * KKP * 4;
  int*   kp_level= (int*)(ws + off);  off += 4ULL * KKP * 4;
  int*   kp_p    = (int*)(ws + off);  off += 4ULL * KKP * 4;
  float* kp_score= (float*)(ws + off); off += 4ULL * KKP * 4;
  float* dA      = (float*)(ws + off); off += 4ULL * KKP * 128 * 4;
  float* S       = (float*)(ws + off); off += 2ULL * KKP * KKP * 4;
  u64*   mcol    = (u64*)(ws + off);  off += 2ULL * CAP_COL * 8;   // ~3.8 MB total

  // zero counters + match histogram (ws is re-poisoned 0xAA before every call)
  hipMemsetAsync(d_ws, 0, 1024 + (size_t)2 * NBINS * 4, stream);

  cand_kernel<<<dim3(NTOT / 256, 4), 256, 0, stream>>>(P, cand, cnt_cand);
  kp_select<<<4, 1024, 0, stream>>>(cand, cnt_cand, kp_loc, kp_level, kp_p, kp_score);
  gather_kernel<<<dim3(KKP, 4), 128, 0, stream>>>(P, kp_level, kp_p, kp_score, dA);
  gemm_kernel<<<dim3(32, 32, 2), dim3(16, 16), 0, stream>>>(dA, S);
  mhist_kernel<<<dim3(16, 2), 1024, 0, stream>>>(S, mhist);
  mscan_kernel<<<2, 1024, 0, stream>>>(mhist, thrB);
  mcollect_kernel<<<dim3(1024, 2), 256, 0, stream>>>(S, thrB, mcol, cnt_match);
  msort_out<<<2, 1024, 0, stream>>>(mcol, cnt_match, kp_loc, (float*)d_out);
}

// Round 3
// 409.724 us; speedup vs baseline: 1.2787x; 1.0060x over previous
//
#include <hip/hip_runtime.h>

typedef unsigned long long u64;
typedef unsigned int u32;

#define N0 147456   // 384*384
#define N1 36864    // 192*192
#define NTOT 184320 // = 720 * 256 exactly
#define KKP 512
#define KM 128
#define CAP_CAND 16384
#define NBINS 16384
#define CAP_COL 2048

struct InPtrs {
  const float* rep[2][2];   // [img][level]
  const float* rel[2][2];
  const float* desc[2][2];
};

// ---------------- candidate generation ----------------
// slot = img*2 + b. Key = (score_bits<<32) | ~pixel_index  ->  descending sort
// == descending score, ties broken by LOWER index (matches lax.top_k).
// Block-aggregated append: LDS atomics + ONE global atomic per block
// (R1 post-mortem: ~37K per-lane atomics on one cacheline = ~133 us serial).
__global__ __launch_bounds__(256) void cand_kernel(InPtrs P, u64* __restrict__ cand,
                                                   int* __restrict__ cnt) {
  __shared__ u64 buf[256];
  __shared__ int lcnt, gbase;
  int slot = blockIdx.y;
  int img = slot >> 1, b = slot & 1;
  int p = blockIdx.x * 256 + threadIdx.x;   // NTOT == 720*256, no tail
  if (threadIdx.x == 0) lcnt = 0;
  __syncthreads();
  int level, W, q, Npix;
  if (p < N0) { level = 0; W = 384; q = p; Npix = N0; }
  else        { level = 1; W = 192; q = p - N0; Npix = N1; }
  const float* rp = P.rep[img][level] + (size_t)b * Npix;
  const float* rl = P.rel[img][level] + (size_t)b * Npix;
  float v = rp[q];
  float m = sqrtf(v * rl[q]);
  bool ok = (m >= 0.7f);
  if (ok) {
    int y = q / W, x = q - y * W;   // square levels: H == W
    int y0 = (y > 0) ? y - 1 : y, y1 = (y < W - 1) ? y + 1 : y;
    int x0 = (x > 0) ? x - 1 : x, x1 = (x < W - 1) ? x + 1 : x;
    for (int yy = y0; yy <= y1 && ok; ++yy)
      for (int xx = x0; xx <= x1; ++xx)
        if (rp[yy * W + xx] > v) { ok = false; break; }
  }
  if (ok) {
    u32 sb = __float_as_uint(m);
    int pos = atomicAdd(&lcnt, 1);          // LDS atomic: cheap, per-CU
    buf[pos] = ((u64)sb << 32) | (u32)(~(u32)p);
  }
  __syncthreads();
  if (threadIdx.x == 0) gbase = lcnt ? atomicAdd(&cnt[slot * 16], lcnt) : 0;
  __syncthreads();
  int n = lcnt;
  if ((int)threadIdx.x < n) {
    int pos = gbase + (int)threadIdx.x;
    if (pos < CAP_CAND) cand[(size_t)slot * CAP_CAND + pos] = buf[threadIdx.x];
  }
}

// ---------------- bitonic sort of 2048 u64 keys in LDS, descending ----------------
__device__ inline void bitonic2048(u64* k, int t) {
  for (int size = 2; size <= 2048; size <<= 1) {
    for (int j = size >> 1; j > 0; j >>= 1) {
      __syncthreads();
      for (int i = t; i < 2048; i += 1024) {
        int ixj = i ^ j;
        if (ixj > i) {
          u64 a = k[i], b = k[ixj];
          bool desc = ((i & size) == 0);
          if (desc ? (a < b) : (a > b)) { k[i] = b; k[ixj] = a; }
        }
      }
    }
  }
  __syncthreads();
}

// ---------------- keypoint top-512: radix-select + exact sort + decode ----------------
// histogram bin = (key >> 41) & 16383 = top-14 mantissa bits; all scores are in
// [0.7,1) (exponent 126) so this is monotone. Fused decode epilogue.
__global__ __launch_bounds__(1024) void kp_select(const u64* __restrict__ keys_all,
                                                  const int* __restrict__ cnt,
                                                  float* __restrict__ kp_loc,
                                                  int* __restrict__ kp_level,
                                                  int* __restrict__ kp_p,
                                                  float* __restrict__ kp_score) {
  __shared__ int hist[NBINS];
  __shared__ u64 kbuf[CAP_COL];
  __shared__ int part[1024];
  __shared__ int Bbin, colcnt;
  int slot = blockIdx.x;
  int t = threadIdx.x;
  const u64* keys = keys_all + (size_t)slot * CAP_CAND;
  int n = cnt[slot * 16]; if (n > CAP_CAND) n = CAP_CAND;
  for (int i = t; i < NBINS; i += 1024) hist[i] = 0;
  if (t == 0) { Bbin = 0; colcnt = 0; }
  __syncthreads();
  for (int i = t; i < n; i += 1024) {
    u32 bin = (u32)((keys[i] >> 41) & (NBINS - 1));
    atomicAdd(&hist[bin], 1);
  }
  __syncthreads();
  const int BPT = NBINS / 1024;
  int base = t * BPT;
  int lsum = 0;
  for (int j = 0; j < BPT; ++j) lsum += hist[base + j];
  part[t] = lsum;
  __syncthreads();
  for (int off = 1; off < 1024; off <<= 1) {   // suffix scan
    int v = (t + off < 1024) ? part[t + off] : 0;
    __syncthreads();
    part[t] += v;
    __syncthreads();
  }
  int Sab = part[t] - lsum;   // count strictly above my bin range
  if (Sab < KKP && Sab + lsum >= KKP) {
    int c = Sab;
    for (int j = BPT - 1; j >= 0; --j) {
      c += hist[base + j];
      if (c >= KKP) { Bbin = base + j; break; }
    }
  }
  __syncthreads();
  int Bb = Bbin;
  for (int i = t; i < n; i += 1024) {
    u64 kk = keys[i];
    if ((int)((kk >> 41) & (NBINS - 1)) >= Bb) {
      int pos = atomicAdd(&colcnt, 1);
      if (pos < CAP_COL) kbuf[pos] = kk;
    }
  }
  __syncthreads();
  int nc = colcnt; if (nc > CAP_COL) nc = CAP_COL;
  for (int i = t; i < CAP_COL; i += 1024) if (i >= nc) kbuf[i] = 0;
  __syncthreads();
  bitonic2048(kbuf, t);
  // fused decode (t < 512)
  if (t < KKP) {
    u64 key = kbuf[t];
    float s = __uint_as_float((u32)(key >> 32));
    u32 idx = ~(u32)key;
    int level, p, W, scale;
    if (idx < N0) { level = 0; p = (int)idx; W = 384; scale = 1; }
    else          { level = 1; p = (int)(idx - N0); W = 192; scale = 2; }
    if (p < 0 || p >= (level ? N1 : N0)) { p = 0; s = 0.f; }  // pad guard
    int y = p / W, x = p - y * W;
    kp_loc[(slot * 2 + 0) * KKP + t] = (float)(y * scale);
    kp_loc[(slot * 2 + 1) * KKP + t] = (float)(x * scale);
    kp_level[slot * KKP + t] = level;
    kp_p[slot * KKP + t] = p;
    kp_score[slot * KKP + t] = s;
  }
}

// ---------------- gather descriptors * score (TRANSPOSED out: dAt[slot][c][k]) ----------
// Reads are inherently scattered (random p); writes coalesced over k. The
// transposed layout feeds gemm's LDS staging with coalesced, conflict-free loads.
__global__ __launch_bounds__(512) void gather_kernel(InPtrs P, const int* __restrict__ kp_level,
                                                     const int* __restrict__ kp_p,
                                                     const float* __restrict__ kp_score,
                                                     float* __restrict__ dAt) {
  int slot = blockIdx.y;
  int c = blockIdx.x;       // 0..127 channel
  int k = threadIdx.x;      // 0..511 keypoint
  int img = slot >> 1, b = slot & 1;
  int level = kp_level[slot * KKP + k];
  int p = kp_p[slot * KKP + k];
  float s = kp_score[slot * KKP + k];
  const float* dptr = P.desc[img][level];
  size_t HW = level ? N1 : N0;
  float v = dptr[((size_t)b * 128 + c) * HW + p];
  dAt[((size_t)slot * 128 + c) * KKP + k] = v * s;
}

// ---------------- fp32 GEMM: S[b][k][l] = sum_c A_t[c][k]*B_t[c][l] ----------------
// 64x64 tile / block(16x16), 4x4 acc per thread, float4 LDS fragments.
// A-fragment: 4 distinct addrs/wave (broadcast, ~free); B-fragment: 16 addrs = 2-way (free).
__global__ __launch_bounds__(256) void gemm_kernel(const float* __restrict__ dAt,
                                                   float* __restrict__ S) {
  __shared__ float tA[128][68];   // [c][row], 68 = 64 + 4 pad (16B-aligned rows)
  __shared__ float tB[128][68];
  int b = blockIdx.z;
  const float* A  = dAt + (size_t)b * 128 * KKP;        // slot img0 = b
  const float* Bm = dAt + (size_t)(2 + b) * 128 * KKP;  // slot img1 = 2+b
  int row0 = blockIdx.y * 64, col0 = blockIdx.x * 64;
  int t = threadIdx.y * 16 + threadIdx.x;
  for (int i = t; i < 2048; i += 256) {                 // 128c x 16 float4
    int c = i >> 4, r4 = (i & 15) << 2;
    *(float4*)&tA[c][r4] = *(const float4*)&A[c * KKP + row0 + r4];
    *(float4*)&tB[c][r4] = *(const float4*)&Bm[c * KKP + col0 + r4];
  }
  __syncthreads();
  float acc[4][4] = {};
  int ra = threadIdx.y * 4, rb = threadIdx.x * 4;
  for (int k = 0; k < 128; ++k) {
    float4 a4 = *(const float4*)&tA[k][ra];
    float4 b4 = *(const float4*)&tB[k][rb];
    float a[4] = {a4.x, a4.y, a4.z, a4.w};
    float bb[4] = {b4.x, b4.y, b4.z, b4.w};
    for (int i = 0; i < 4; ++i)
      for (int j = 0; j < 4; ++j)
        acc[i][j] += a[i] * bb[j];
  }
  for (int i = 0; i < 4; ++i) {
    float4 v = {acc[i][0], acc[i][1], acc[i][2], acc[i][3]};
    *(float4*)&S[(size_t)b * KKP * KKP + (size_t)(row0 + ra + i) * KKP + (col0 + rb)] = v;
  }
}

// ---------------- match histogram (order-preserving float->u32, bin = key>>18) ----------------
__device__ inline u32 fkey32(float v) {
  u32 bits = __float_as_uint(v);
  return (bits & 0x80000000u) ? ~bits : (bits | 0x80000000u);
}

__global__ __launch_bounds__(1024) void mhist_kernel(const float* __restrict__ S, int* __restrict__ hist) {
  __shared__ int lh[NBINS];
  int t = threadIdx.x;
  for (int i = t; i < NBINS; i += 1024) lh[i] = 0;
  __syncthreads();
  int b = blockIdx.y;
  const float* Sb = S + (size_t)b * KKP * KKP;
  int base = blockIdx.x * 8192;
  for (int i = 0; i < 8; ++i) {
    u32 key = fkey32(Sb[base + i * 1024 + t]);
    atomicAdd(&lh[key >> 18], 1);
  }
  __syncthreads();
  for (int i = t; i < NBINS; i += 1024) {
    int v = lh[i];
    if (v) atomicAdd(&hist[b * NBINS + i], v);
  }
}

__global__ __launch_bounds__(1024) void mscan_kernel(const int* __restrict__ hist, int* __restrict__ thrB) {
  __shared__ int part[1024];
  __shared__ int Bbin;
  int b = blockIdx.x;
  int t = threadIdx.x;
  const int* h = hist + b * NBINS;
  if (t == 0) Bbin = 0;
  const int BPT = NBINS / 1024;
  int base = t * BPT;
  int lsum = 0;
  for (int j = 0; j < BPT; ++j) lsum += h[base + j];
  part[t] = lsum;
  __syncthreads();
  for (int off = 1; off < 1024; off <<= 1) {
    int v = (t + off < 1024) ? part[t + off] : 0;
    __syncthreads();
    part[t] += v;
    __syncthreads();
  }
  int Sab = part[t] - lsum;
  if (Sab < KM && Sab + lsum >= KM) {
    int c = Sab;
    for (int j = BPT - 1; j >= 0; --j) {
      c += h[base + j];
      if (c >= KM) { Bbin = base + j; break; }
    }
  }
  __syncthreads();
  if (t == 0) thrB[b] = Bbin;
}

// block-aggregated collect (same LDS-append pattern as cand_kernel)
__global__ __launch_bounds__(256) void mcollect_kernel(const float* __restrict__ S,
                                                       const int* __restrict__ thrB,
                                                       u64* __restrict__ mcol,
                                                       int* __restrict__ cnt) {
  __shared__ u64 buf[256];
  __shared__ int lcnt, gbase;
  int b = blockIdx.y;
  int flat = blockIdx.x * 256 + threadIdx.x;   // < 262144
  if (threadIdx.x == 0) lcnt = 0;
  __syncthreads();
  u32 key32 = fkey32(S[(size_t)b * KKP * KKP + flat]);
  if ((int)(key32 >> 18) >= thrB[b]) {
    int pos = atomicAdd(&lcnt, 1);
    buf[pos] = ((u64)key32 << 32) | (u32)(~(u32)flat);
  }
  __syncthreads();
  if (threadIdx.x == 0) gbase = lcnt ? atomicAdd(&cnt[b * 16], lcnt) : 0;
  __syncthreads();
  int n = lcnt;
  if ((int)threadIdx.x < n) {
    int pos = gbase + (int)threadIdx.x;
    if (pos < CAP_COL) mcol[(size_t)b * CAP_COL + pos] = buf[threadIdx.x];
  }
}

__global__ __launch_bounds__(1024) void msort_out(const u64* __restrict__ mcol, const int* __restrict__ cnt,
                                                  const float* __restrict__ kp_loc, float* __restrict__ out) {
  __shared__ u64 kbuf[CAP_COL];
  int b = blockIdx.x;
  int t = threadIdx.x;
  int n = cnt[b * 16]; if (n > CAP_COL) n = CAP_COL;
  for (int i = t; i < CAP_COL; i += 1024) kbuf[i] = (i < n) ? mcol[(size_t)b * CAP_COL + i] : 0ULL;
  __syncthreads();
  bitonic2048(kbuf, t);
  if (t < KM) {
    u64 key = kbuf[t];
    u32 flat = ~(u32)key;
    int i1 = (int)(flat >> 9), i2 = (int)(flat & 511);
    if (i1 >= KKP) { i1 = 0; i2 = 0; }  // pad guard (never hit: 262144 finite scores)
    int slot1 = b, slot2 = 2 + b;
    out[(b * 4 + 0) * KM + t] = kp_loc[(slot1 * 2 + 0) * KKP + i1];
    out[(b * 4 + 1) * KM + t] = kp_loc[(slot1 * 2 + 1) * KKP + i1];
    out[(b * 4 + 2) * KM + t] = kp_loc[(slot2 * 2 + 0) * KKP + i2];
    out[(b * 4 + 3) * KM + t] = kp_loc[(slot2 * 2 + 1) * KKP + i2];
  }
}

extern "C" void kernel_launch(void* const* d_in, const int* in_sizes, int n_in,
                              void* d_out, int out_size, void* d_ws, size_t ws_size,
                              hipStream_t stream) {
  (void)in_sizes; (void)n_in; (void)out_size; (void)ws_size;
  InPtrs P;
  P.rep[0][0] = (const float*)d_in[0];  P.rel[0][0] = (const float*)d_in[1];  P.desc[0][0] = (const float*)d_in[2];
  P.rep[0][1] = (const float*)d_in[3];  P.rel[0][1] = (const float*)d_in[4];  P.desc[0][1] = (const float*)d_in[5];
  P.rep[1][0] = (const float*)d_in[6];  P.rel[1][0] = (const float*)d_in[7];  P.desc[1][0] = (const float*)d_in[8];
  P.rep[1][1] = (const float*)d_in[9];  P.rel[1][1] = (const float*)d_in[10]; P.desc[1][1] = (const float*)d_in[11];

  char* ws = (char*)d_ws;
  // counters: each slot's counter on its own 64B cacheline (stride-16 ints)
  int*   cnt_cand  = (int*)(ws + 0);      // cnt_cand[slot*16], 4 slots -> 256B
  int*   cnt_match = (int*)(ws + 256);    // cnt_match[b*16], 2 -> 128B
  int*   thrB      = (int*)(ws + 512);    // 2 ints
  int*   mhist     = (int*)(ws + 1024);   // 2*16384*4 = 131072
  size_t off = 1024 + (size_t)2 * NBINS * 4;               // zeroed region end
  u64*   cand    = (u64*)(ws + off);  off += 4ULL * CAP_CAND * 8;
  float* kp_loc  = (float*)(ws + off); off += 4ULL * 2 * KKP * 4;
  int*   kp_level= (int*)(ws + off);  off += 4ULL * KKP * 4;
  int*   kp_p    = (int*)(ws + off);  off += 4ULL * KKP * 4;
  float* kp_score= (float*)(ws + off); off += 4ULL * KKP * 4;
  float* dAt     = (float*)(ws + off); off += 4ULL * KKP * 128 * 4;
  float* S       = (float*)(ws + off); off += 2ULL * KKP * KKP * 4;
  u64*   mcol    = (u64*)(ws + off);  off += 2ULL * CAP_COL * 8;   // ~3.8 MB total

  // zero counters + match histogram (ws is re-poisoned 0xAA before every call)
  hipMemsetAsync(d_ws, 0, 1024 + (size_t)2 * NBINS * 4, stream);

  cand_kernel<<<dim3(NTOT / 256, 4), 256, 0, stream>>>(P, cand, cnt_cand);
  kp_select<<<4, 1024, 0, stream>>>(cand, cnt_cand, kp_loc, kp_level, kp_p, kp_score);
  gather_kernel<<<dim3(128, 4), 512, 0, stream>>>(P, kp_level, kp_p, kp_score, dAt);
  gemm_kernel<<<dim3(8, 8, 2), dim3(16, 16), 0, stream>>>(dAt, S);
  mhist_kernel<<<dim3(32, 2), 1024, 0, stream>>>(S, mhist);
  mscan_kernel<<<2, 1024, 0, stream>>>(mhist, thrB);
  mcollect_kernel<<<dim3(1024, 2), 256, 0, stream>>>(S, thrB, mcol, cnt_match);
  msort_out<<<2, 1024, 0, stream>>>(mcol, cnt_match, kp_loc, (float*)d_out);
}